// Round 1
// baseline (803.394 us; speedup 1.0000x reference)
//
#include <hip/hip_runtime.h>
#include <cstddef>

#define BB 4
#define LSEQ 2304      // 48*48
#define DM 128
#define DI 256
#define NST 16
#define DTR 8
#define NC 72          // chunks
#define CT 32          // chunk length; NC*CT == LSEQ

// ---------------- prep: x_i = x_slice + prev, also write transposed copy + local mean ----------------
__global__ __launch_bounds__(256) void k_prep(const float* __restrict__ x,
                                              const float* __restrict__ prev, int scale,
                                              float* __restrict__ x_i, float* __restrict__ spT,
                                              float* __restrict__ wl) {
    int bc = blockIdx.x;               // b*128 + c
    int b = bc >> 7, c = bc & 127;
    const float* src = x + ((size_t)(b * 512 + scale * 128 + c)) * LSEQ;
    const float* pv = prev ? prev + ((size_t)(b * 512 + (scale - 1) * 128 + c)) * LSEQ : nullptr;
    float sum = 0.f;
    for (int l = threadIdx.x; l < LSEQ; l += 256) {
        float v = src[l] + (pv ? pv[l] : 0.f);
        x_i[(size_t)bc * LSEQ + l] = v;
        spT[((size_t)(b * LSEQ + l)) * DM + c] = v;
        sum += v;
    }
    __shared__ float red[256];
    red[threadIdx.x] = sum;
    __syncthreads();
    for (int s = 128; s > 0; s >>= 1) {
        if (threadIdx.x < s) red[threadIdx.x] += red[threadIdx.x + s];
        __syncthreads();
    }
    if (threadIdx.x == 0) {
        float m = red[0] / (float)LSEQ;
        wl[bc] = 1.f / (1.f + __expf(-m));
    }
}

// ---------------- generic tiled GEMM: C[M,N] = A[M,K] * W[N,K]^T ----------------
// 64x64 tile, K-tile 32, 256 threads, 4x4 microtile. M % 64 == 0, K % 32 == 0 assumed.
__global__ __launch_bounds__(256) void k_gemm(const float* __restrict__ A, const float* __restrict__ W,
                                              float* __restrict__ Cout, int M, int N, int K) {
    __shared__ float As[32][68];
    __shared__ float Ws[32][68];
    int tid = threadIdx.x;
    int n0 = blockIdx.x * 64;
    int m0 = blockIdx.y * 64;
    int tn = (tid & 15) * 4;
    int tm = (tid >> 4) * 4;
    int p = tid & 7, q = tid >> 3;     // p: k-quad, q: row 0..31
    float acc[4][4] = {{0.f}};
    for (int k0 = 0; k0 < K; k0 += 32) {
        #pragma unroll
        for (int h = 0; h < 2; ++h) {
            int m = q + 32 * h;
            const float4 av = *(const float4*)(A + (size_t)(m0 + m) * K + k0 + 4 * p);
            As[4 * p + 0][m] = av.x; As[4 * p + 1][m] = av.y;
            As[4 * p + 2][m] = av.z; As[4 * p + 3][m] = av.w;
        }
        #pragma unroll
        for (int h = 0; h < 2; ++h) {
            int n = q + 32 * h;
            float4 wv = make_float4(0.f, 0.f, 0.f, 0.f);
            if (n0 + n < N) wv = *(const float4*)(W + (size_t)(n0 + n) * K + k0 + 4 * p);
            Ws[4 * p + 0][n] = wv.x; Ws[4 * p + 1][n] = wv.y;
            Ws[4 * p + 2][n] = wv.z; Ws[4 * p + 3][n] = wv.w;
        }
        __syncthreads();
        #pragma unroll
        for (int k = 0; k < 32; ++k) {
            float4 a4 = *(const float4*)&As[k][tm];
            float4 w4 = *(const float4*)&Ws[k][tn];
            acc[0][0] += a4.x * w4.x; acc[0][1] += a4.x * w4.y; acc[0][2] += a4.x * w4.z; acc[0][3] += a4.x * w4.w;
            acc[1][0] += a4.y * w4.x; acc[1][1] += a4.y * w4.y; acc[1][2] += a4.y * w4.z; acc[1][3] += a4.y * w4.w;
            acc[2][0] += a4.z * w4.x; acc[2][1] += a4.z * w4.y; acc[2][2] += a4.z * w4.z; acc[2][3] += a4.z * w4.w;
            acc[3][0] += a4.w * w4.x; acc[3][1] += a4.w * w4.y; acc[3][2] += a4.w * w4.z; acc[3][3] += a4.w * w4.w;
        }
        __syncthreads();
    }
    #pragma unroll
    for (int im = 0; im < 4; ++im) {
        int m = m0 + tm + im;
        #pragma unroll
        for (int jn = 0; jn < 4; ++jn) {
            int n = n0 + tn + jn;
            if (n < N) Cout[(size_t)m * N + n] = acc[im][jn];
        }
    }
}

// ---------------- depthwise causal conv (k=4) + bias + SiLU ----------------
__global__ __launch_bounds__(256) void k_conv(const float* __restrict__ xz, const float* __restrict__ wc,
                                              const float* __restrict__ bcv, float* __restrict__ xs) {
    size_t t = (size_t)blockIdx.x * 256 + threadIdx.x;   // B*L*256
    int d = (int)(t & 255);
    size_t bl = t >> 8;
    int l = (int)(bl % LSEQ);
    float acc = bcv[d];
    #pragma unroll
    for (int j = 0; j < 4; ++j) {
        int ll = l - 3 + j;
        if (ll >= 0) acc += wc[d * 4 + j] * xz[(bl - 3 + j) * 512 + d];
    }
    xs[bl * 256 + d] = acc / (1.f + __expf(-acc));
}

// ---------------- dt projection + softplus ----------------
__global__ __launch_bounds__(256) void k_dt(const float* __restrict__ dbc, const float* __restrict__ Wdt,
                                            const float* __restrict__ bdt, float* __restrict__ delta) {
    size_t t = (size_t)blockIdx.x * 256 + threadIdx.x;   // B*L*256
    int d = (int)(t & 255);
    size_t bl = t >> 8;
    const float* r = dbc + bl * 40;
    float acc = bdt[d];
    #pragma unroll
    for (int j = 0; j < 8; ++j) acc += r[j] * Wdt[d * 8 + j];
    delta[bl * 256 + d] = fmaxf(acc, 0.f) + log1pf(__expf(-fabsf(acc)));
}

// ---------------- scan pass 1: per-chunk (prod dA, local state) ----------------
__global__ __launch_bounds__(256) void k_scan1(const float* __restrict__ delta, const float* __restrict__ xs,
                                               const float* __restrict__ dbc, const float* __restrict__ Alog,
                                               float* __restrict__ Pb, float* __restrict__ Sb) {
    int d = threadIdx.x;
    int c = blockIdx.x, b = blockIdx.y;
    float a[NST], P[NST], S[NST];
    #pragma unroll
    for (int n = 0; n < NST; ++n) {
        a[n] = -__expf(Alog[d * NST + n]);
        P[n] = 1.f; S[n] = 0.f;
    }
    int l0 = c * CT;
    for (int l = l0; l < l0 + CT; ++l) {
        size_t row = (size_t)b * LSEQ + l;
        float dv = delta[row * 256 + d];
        float xv = xs[row * 256 + d];
        float du = dv * xv;
        const float* bp = dbc + row * 40 + 8;
        #pragma unroll
        for (int n = 0; n < NST; ++n) {
            float Bn = bp[n];
            float dA = __expf(dv * a[n]);
            P[n] *= dA;
            S[n] = dA * S[n] + du * Bn;
        }
    }
    size_t base = ((size_t)(b * NC + c) * NST) * 256 + d;
    #pragma unroll
    for (int n = 0; n < NST; ++n) { Pb[base + (size_t)n * 256] = P[n]; Sb[base + (size_t)n * 256] = S[n]; }
}

// ---------------- scan pass 2: serial chunk combine ----------------
__global__ __launch_bounds__(256) void k_scan2(const float* __restrict__ Pb, const float* __restrict__ Sb,
                                               float* __restrict__ H0) {
    int d = threadIdx.x;
    int b = blockIdx.x;
    float h[NST];
    #pragma unroll
    for (int n = 0; n < NST; ++n) h[n] = 0.f;
    for (int c = 0; c < NC; ++c) {
        size_t base = ((size_t)(b * NC + c) * NST) * 256 + d;
        #pragma unroll
        for (int n = 0; n < NST; ++n) {
            size_t idx = base + (size_t)n * 256;
            H0[idx] = h[n];
            h[n] = Pb[idx] * h[n] + Sb[idx];
        }
    }
}

// ---------------- scan pass 3: replay with correct start state + D-skip + SiLU(z) gate ----------------
__global__ __launch_bounds__(256) void k_scan3(const float* __restrict__ delta, const float* __restrict__ xs,
                                               const float* __restrict__ dbc, const float* __restrict__ Alog,
                                               const float* __restrict__ Dp, const float* __restrict__ xz,
                                               const float* __restrict__ H0, float* __restrict__ yb) {
    int d = threadIdx.x;
    int c = blockIdx.x, b = blockIdx.y;
    float a[NST], h[NST];
    size_t base = ((size_t)(b * NC + c) * NST) * 256 + d;
    #pragma unroll
    for (int n = 0; n < NST; ++n) {
        a[n] = -__expf(Alog[d * NST + n]);
        h[n] = H0[base + (size_t)n * 256];
    }
    float Dv = Dp[d];
    int l0 = c * CT;
    for (int l = l0; l < l0 + CT; ++l) {
        size_t row = (size_t)b * LSEQ + l;
        float dv = delta[row * 256 + d];
        float xv = xs[row * 256 + d];
        float du = dv * xv;
        const float* bp = dbc + row * 40 + 8;
        const float* cp = bp + NST;
        float y = 0.f;
        #pragma unroll
        for (int n = 0; n < NST; ++n) {
            float dA = __expf(dv * a[n]);
            h[n] = dA * h[n] + du * bp[n];
            y += h[n] * cp[n];
        }
        float z = xz[row * 512 + 256 + d];
        float sz = z / (1.f + __expf(-z));
        yb[row * 256 + d] = (y + xv * Dv) * sz;
    }
}

// ---------------- cdgf: global mean of max(x_i, x_m) ----------------
__global__ __launch_bounds__(256) void k_mg(const float* __restrict__ x_i, const float* __restrict__ xm,
                                            float* __restrict__ wg) {
    int bc = blockIdx.x;
    int b = bc >> 7, c = bc & 127;
    float sum = 0.f;
    for (int l = threadIdx.x; l < LSEQ; l += 256) {
        float xi = x_i[(size_t)bc * LSEQ + l];
        float xv = xm[((size_t)(b * LSEQ + l)) * DM + c];
        sum += fmaxf(xi, xv);
    }
    __shared__ float red[256];
    red[threadIdx.x] = sum;
    __syncthreads();
    for (int s = 128; s > 0; s >>= 1) {
        if (threadIdx.x < s) red[threadIdx.x] += red[threadIdx.x + s];
        __syncthreads();
    }
    if (threadIdx.x == 0) {
        float m = red[0] / (float)LSEQ;
        wg[bc] = 1.f / (1.f + __expf(-m));
    }
}

// ---------------- cdgf elementwise output ----------------
__global__ __launch_bounds__(256) void k_out(const float* __restrict__ x_i, const float* __restrict__ xm,
                                             const float* __restrict__ wl, const float* __restrict__ wg,
                                             float* __restrict__ out, int scale) {
    size_t t = (size_t)blockIdx.x * 256 + threadIdx.x;   // B*128*L
    int l = (int)(t % LSEQ);
    int bc = (int)(t / LSEQ);
    int b = bc >> 7, c = bc & 127;
    float xi = x_i[t];
    float xv = xm[((size_t)(b * LSEQ + l)) * DM + c];
    float fg = fmaxf(xi, xv);
    out[((size_t)(b * 512 + scale * 128 + c)) * LSEQ + l] = wl[bc] * xi + wg[bc] * fg;
}

extern "C" void kernel_launch(void* const* d_in, const int* in_sizes, int n_in,
                              void* d_out, int out_size, void* d_ws, size_t ws_size,
                              hipStream_t stream) {
    const float* x    = (const float*)d_in[0];
    const float* Wi   = (const float*)d_in[1];   // (4, 512, 128)
    const float* wc   = (const float*)d_in[2];   // (4, 256, 4)
    const float* bcv  = (const float*)d_in[3];   // (4, 256)
    const float* Wx   = (const float*)d_in[4];   // (4, 40, 256)
    const float* Wdt  = (const float*)d_in[5];   // (4, 256, 8)
    const float* bdt  = (const float*)d_in[6];   // (4, 256)
    const float* Alog = (const float*)d_in[7];   // (4, 256, 16)
    const float* Dp   = (const float*)d_in[8];   // (4, 256)
    const float* Wo   = (const float*)d_in[9];   // (4, 128, 256)
    float* out = (float*)d_out;
    float* w = (float*)d_ws;

    // ws layout (floats)
    float* x_i   = w;                      // 1,179,648  (B*128*L)
    float* xz    = x_i + 1179648;          // 4,718,592  (B*L*512)
    float* xs_   = xz + 4718592;           // 2,359,296  (B*L*256)
    float* dbc   = xs_ + 2359296;          // 368,640    (B*L*40)
    float* delta = dbc + 368640;           // 2,359,296  (B*L*256)
    float* yb    = delta + 2359296;        // 2,359,296  (B*L*256); spT aliases first half
    float* Pb    = yb + 2359296;           // 1,179,648  (B*NC*16*256)
    float* Sb    = Pb + 1179648;           // 1,179,648
    float* H0    = Sb + 1179648;           // 1,179,648
    float* wl    = H0 + 1179648;           // 512
    float* wg    = wl + 512;               // 512
    float* spT   = yb;                     // alias (B*L*128), disjoint lifetime from yb
    float* xm    = xz;                     // alias (B*L*128), xz dead after scan3

    for (int i = 0; i < 4; ++i) {
        const float* Wi_i   = Wi   + (size_t)i * 512 * 128;
        const float* wc_i   = wc   + (size_t)i * 256 * 4;
        const float* bc_i   = bcv  + (size_t)i * 256;
        const float* Wx_i   = Wx   + (size_t)i * 40 * 256;
        const float* Wdt_i  = Wdt  + (size_t)i * 256 * 8;
        const float* bdt_i  = bdt  + (size_t)i * 256;
        const float* Alog_i = Alog + (size_t)i * 256 * 16;
        const float* D_i    = Dp   + (size_t)i * 256;
        const float* Wo_i   = Wo   + (size_t)i * 128 * 256;

        k_prep<<<512, 256, 0, stream>>>(x, i ? out : nullptr, i, x_i, spT, wl);
        k_gemm<<<dim3(8, 144), 256, 0, stream>>>(spT, Wi_i, xz, 9216, 512, 128);
        k_conv<<<9216, 256, 0, stream>>>(xz, wc_i, bc_i, xs_);
        k_gemm<<<dim3(1, 144), 256, 0, stream>>>(xs_, Wx_i, dbc, 9216, 40, 256);
        k_dt<<<9216, 256, 0, stream>>>(dbc, Wdt_i, bdt_i, delta);
        k_scan1<<<dim3(NC, BB), 256, 0, stream>>>(delta, xs_, dbc, Alog_i, Pb, Sb);
        k_scan2<<<BB, 256, 0, stream>>>(Pb, Sb, H0);
        k_scan3<<<dim3(NC, BB), 256, 0, stream>>>(delta, xs_, dbc, Alog_i, D_i, xz, H0, yb);
        k_gemm<<<dim3(2, 144), 256, 0, stream>>>(yb, Wo_i, xm, 9216, 128, 256);
        k_mg<<<512, 256, 0, stream>>>(x_i, xm, wg);
        k_out<<<4608, 256, 0, stream>>>(x_i, xm, wl, wg, out, i);
    }
}

// Round 2
// 785.142 us; speedup vs baseline: 1.0232x; 1.0232x over previous
//
#include <hip/hip_runtime.h>
#include <cstddef>

#define BB 4
#define LSEQ 2304      // 48*48
#define DM 128
#define DI 256
#define NST 16
#define NC 72          // chunks
#define CT 32          // chunk length; NC*CT == LSEQ

typedef __attribute__((ext_vector_type(8))) short bf16x8;
typedef __attribute__((ext_vector_type(4))) float f32x4;

__device__ __forceinline__ unsigned short f2bf(float f) {
    unsigned u = __float_as_uint(f);
    unsigned r = (u + 0x7fffu + ((u >> 16) & 1u)) >> 16;
    return (unsigned short)r;
}

// ---------------- f32 -> bf16 weight conversion ----------------
__global__ __launch_bounds__(256) void k_cvt(const float* __restrict__ s, unsigned short* __restrict__ d, int n) {
    int i = blockIdx.x * 256 + threadIdx.x;
    if (i < n) d[i] = f2bf(s[i]);
}

// ---------------- prep: x_i = x_slice + prev (f32), spT bf16 transposed, local mean ----------------
__global__ __launch_bounds__(256) void k_prep(const float* __restrict__ x,
                                              const float* __restrict__ prev, int scale,
                                              float* __restrict__ x_i, unsigned short* __restrict__ spT,
                                              float* __restrict__ wl) {
    int bc = blockIdx.x;               // b*128 + c
    int b = bc >> 7, c = bc & 127;
    const float* src = x + ((size_t)(b * 512 + scale * 128 + c)) * LSEQ;
    const float* pv = prev ? prev + ((size_t)(b * 512 + (scale - 1) * 128 + c)) * LSEQ : nullptr;
    float sum = 0.f;
    for (int l = threadIdx.x; l < LSEQ; l += 256) {
        float v = src[l] + (pv ? pv[l] : 0.f);
        x_i[(size_t)bc * LSEQ + l] = v;
        spT[((size_t)(b * LSEQ + l)) * DM + c] = f2bf(v);
        sum += v;
    }
    __shared__ float red[256];
    red[threadIdx.x] = sum;
    __syncthreads();
    for (int s = 128; s > 0; s >>= 1) {
        if (threadIdx.x < s) red[threadIdx.x] += red[threadIdx.x + s];
        __syncthreads();
    }
    if (threadIdx.x == 0) {
        float m = red[0] / (float)LSEQ;
        wl[bc] = 1.f / (1.f + __expf(-m));
    }
}

// ---------------- bf16 MFMA GEMM: C[M,N] = A[M,K] * W[N,K]^T ----------------
// 256 thr = 4 waves; block tile 128x64; wave tile 32x64 (acc[2][4] of 16x16).
// M%128==0, K%32==0; N guarded.
__global__ __launch_bounds__(256) void k_gemm_mfma(const unsigned short* __restrict__ A,
                                                   const unsigned short* __restrict__ W,
                                                   float* __restrict__ C, int M, int N, int K) {
    int wave = threadIdx.x >> 6, lane = threadIdx.x & 63;
    int m0 = blockIdx.y * 128 + wave * 32;
    int n0 = blockIdx.x * 64;
    int row = lane & 15, kq = lane >> 4;
    f32x4 acc[2][4];
    #pragma unroll
    for (int i = 0; i < 2; ++i)
        #pragma unroll
        for (int j = 0; j < 4; ++j) acc[i][j] = (f32x4){0.f, 0.f, 0.f, 0.f};

    for (int k0 = 0; k0 < K; k0 += 32) {
        bf16x8 af[2], bfr[4];
        #pragma unroll
        for (int i = 0; i < 2; ++i)
            af[i] = *(const bf16x8*)(A + (size_t)(m0 + i * 16 + row) * K + k0 + kq * 8);
        #pragma unroll
        for (int j = 0; j < 4; ++j) {
            int n = n0 + j * 16 + row;
            if (n < N) bfr[j] = *(const bf16x8*)(W + (size_t)n * K + k0 + kq * 8);
            else       bfr[j] = (bf16x8){0, 0, 0, 0, 0, 0, 0, 0};
        }
        #pragma unroll
        for (int i = 0; i < 2; ++i)
            #pragma unroll
            for (int j = 0; j < 4; ++j)
                acc[i][j] = __builtin_amdgcn_mfma_f32_16x16x32_bf16(af[i], bfr[j], acc[i][j], 0, 0, 0);
    }
    int cr = (lane >> 4) * 4, cc = lane & 15;
    #pragma unroll
    for (int i = 0; i < 2; ++i)
        #pragma unroll
        for (int j = 0; j < 4; ++j)
            #pragma unroll
            for (int r = 0; r < 4; ++r) {
                int m = m0 + i * 16 + cr + r;
                int n = n0 + j * 16 + cc;
                if (n < N) C[(size_t)m * N + n] = acc[i][j][r];
            }
}

// ---------------- depthwise causal conv (k=4) + bias + SiLU; dual f32/bf16 out ----------------
__global__ __launch_bounds__(256) void k_conv(const float* __restrict__ xz, const float* __restrict__ wc,
                                              const float* __restrict__ bcv, float* __restrict__ xs,
                                              unsigned short* __restrict__ xsb) {
    size_t t = (size_t)blockIdx.x * 256 + threadIdx.x;   // B*L*256
    int d = (int)(t & 255);
    size_t bl = t >> 8;
    int l = (int)(bl % LSEQ);
    float acc = bcv[d];
    #pragma unroll
    for (int j = 0; j < 4; ++j) {
        int ll = l - 3 + j;
        if (ll >= 0) acc += wc[d * 4 + j] * xz[(bl - 3 + j) * 512 + d];
    }
    float v = acc / (1.f + __expf(-acc));
    xs[bl * 256 + d] = v;
    xsb[bl * 256 + d] = f2bf(v);
}

__device__ __forceinline__ float softplusf(float a) {
    return fmaxf(a, 0.f) + log1pf(__expf(-fabsf(a)));
}

// ---------------- scan pass 1: per-chunk (prod dA, local state); delta inline ----------------
__global__ __launch_bounds__(256) void k_scan1(const float* __restrict__ xs, const float* __restrict__ dbc,
                                               const float* __restrict__ Alog, const float* __restrict__ Wdt,
                                               const float* __restrict__ bdt,
                                               float* __restrict__ Pb, float* __restrict__ Sb) {
    int d = threadIdx.x;
    int c = blockIdx.x, b = blockIdx.y;
    float wdt[8];
    #pragma unroll
    for (int j = 0; j < 8; ++j) wdt[j] = Wdt[d * 8 + j];
    float bd = bdt[d];
    float a[NST], P[NST], S[NST];
    #pragma unroll
    for (int n = 0; n < NST; ++n) {
        a[n] = -__expf(Alog[d * NST + n]);
        P[n] = 1.f; S[n] = 0.f;
    }
    int l0 = c * CT;
    for (int l = l0; l < l0 + CT; ++l) {
        size_t row = (size_t)b * LSEQ + l;
        const float* rp = dbc + row * 40;
        float dt = bd;
        #pragma unroll
        for (int j = 0; j < 8; ++j) dt += rp[j] * wdt[j];
        float dv = softplusf(dt);
        float du = dv * xs[row * 256 + d];
        #pragma unroll
        for (int n = 0; n < NST; ++n) {
            float dA = __expf(dv * a[n]);
            P[n] *= dA;
            S[n] = dA * S[n] + du * rp[8 + n];
        }
    }
    size_t base = ((size_t)(b * NC + c) * NST) * 256 + d;
    #pragma unroll
    for (int n = 0; n < NST; ++n) { Pb[base + (size_t)n * 256] = P[n]; Sb[base + (size_t)n * 256] = S[n]; }
}

// ---------------- scan pass 2: serial chunk combine ----------------
__global__ __launch_bounds__(256) void k_scan2(const float* __restrict__ Pb, const float* __restrict__ Sb,
                                               float* __restrict__ H0) {
    int d = threadIdx.x;
    int b = blockIdx.x;
    float h[NST];
    #pragma unroll
    for (int n = 0; n < NST; ++n) h[n] = 0.f;
    for (int c = 0; c < NC; ++c) {
        size_t base = ((size_t)(b * NC + c) * NST) * 256 + d;
        #pragma unroll
        for (int n = 0; n < NST; ++n) {
            size_t idx = base + (size_t)n * 256;
            H0[idx] = h[n];
            h[n] = Pb[idx] * h[n] + Sb[idx];
        }
    }
}

// ---------------- scan pass 3: replay + D-skip + SiLU(z) gate; bf16 out; delta inline ----------------
__global__ __launch_bounds__(256) void k_scan3(const float* __restrict__ xs, const float* __restrict__ dbc,
                                               const float* __restrict__ Alog, const float* __restrict__ Wdt,
                                               const float* __restrict__ bdt, const float* __restrict__ Dp,
                                               const float* __restrict__ xz, const float* __restrict__ H0,
                                               unsigned short* __restrict__ ybb) {
    int d = threadIdx.x;
    int c = blockIdx.x, b = blockIdx.y;
    float wdt[8];
    #pragma unroll
    for (int j = 0; j < 8; ++j) wdt[j] = Wdt[d * 8 + j];
    float bd = bdt[d];
    float a[NST], h[NST];
    size_t base = ((size_t)(b * NC + c) * NST) * 256 + d;
    #pragma unroll
    for (int n = 0; n < NST; ++n) {
        a[n] = -__expf(Alog[d * NST + n]);
        h[n] = H0[base + (size_t)n * 256];
    }
    float Dv = Dp[d];
    int l0 = c * CT;
    for (int l = l0; l < l0 + CT; ++l) {
        size_t row = (size_t)b * LSEQ + l;
        const float* rp = dbc + row * 40;
        float dt = bd;
        #pragma unroll
        for (int j = 0; j < 8; ++j) dt += rp[j] * wdt[j];
        float dv = softplusf(dt);
        float xv = xs[row * 256 + d];
        float du = dv * xv;
        float y = 0.f;
        #pragma unroll
        for (int n = 0; n < NST; ++n) {
            float dA = __expf(dv * a[n]);
            h[n] = dA * h[n] + du * rp[8 + n];
            y += h[n] * rp[24 + n];
        }
        float z = xz[row * 512 + 256 + d];
        float sz = z / (1.f + __expf(-z));
        ybb[row * 256 + d] = f2bf((y + xv * Dv) * sz);
    }
}

// ---------------- fused cdgf: global mean reduce + elementwise output ----------------
__global__ __launch_bounds__(256) void k_gate(const float* __restrict__ x_i, const float* __restrict__ xm,
                                              const float* __restrict__ wl, float* __restrict__ out,
                                              int scale) {
    int bc = blockIdx.x;
    int b = bc >> 7, c = bc & 127;
    float sum = 0.f;
    for (int l = threadIdx.x; l < LSEQ; l += 256) {
        float xi = x_i[(size_t)bc * LSEQ + l];
        float xv = xm[((size_t)(b * LSEQ + l)) * DM + c];
        sum += fmaxf(xi, xv);
    }
    __shared__ float red[256];
    red[threadIdx.x] = sum;
    __syncthreads();
    for (int s = 128; s > 0; s >>= 1) {
        if (threadIdx.x < s) red[threadIdx.x] += red[threadIdx.x + s];
        __syncthreads();
    }
    __shared__ float wgs;
    if (threadIdx.x == 0) {
        float m = red[0] / (float)LSEQ;
        wgs = 1.f / (1.f + __expf(-m));
    }
    __syncthreads();
    float wgv = wgs;
    float wlv = wl[bc];
    float* dst = out + ((size_t)(b * 512 + scale * 128 + c)) * LSEQ;
    for (int l = threadIdx.x; l < LSEQ; l += 256) {
        float xi = x_i[(size_t)bc * LSEQ + l];
        float xv = xm[((size_t)(b * LSEQ + l)) * DM + c];
        float fg = fmaxf(xi, xv);
        dst[l] = wlv * xi + wgv * fg;
    }
}

extern "C" void kernel_launch(void* const* d_in, const int* in_sizes, int n_in,
                              void* d_out, int out_size, void* d_ws, size_t ws_size,
                              hipStream_t stream) {
    const float* x    = (const float*)d_in[0];
    const float* Wi   = (const float*)d_in[1];   // (4, 512, 128)
    const float* wc   = (const float*)d_in[2];   // (4, 256, 4)
    const float* bcv  = (const float*)d_in[3];   // (4, 256)
    const float* Wx   = (const float*)d_in[4];   // (4, 40, 256)
    const float* Wdt  = (const float*)d_in[5];   // (4, 256, 8)
    const float* bdt  = (const float*)d_in[6];   // (4, 256)
    const float* Alog = (const float*)d_in[7];   // (4, 256, 16)
    const float* Dp   = (const float*)d_in[8];   // (4, 256)
    const float* Wo   = (const float*)d_in[9];   // (4, 128, 256)
    float* out = (float*)d_out;
    float* w = (float*)d_ws;

    // ws layout (floats)
    float* x_i  = w;                    // 1,179,648
    float* xz   = x_i + 1179648;        // 4,718,592
    float* xs_f = xz + 4718592;         // 2,359,296
    float* dbc  = xs_f + 2359296;       // 368,640
    float* xm   = dbc + 368640;         // 1,179,648
    float* Pb   = xm + 1179648;         // 1,179,648
    float* Sb   = Pb + 1179648;         // 1,179,648
    float* H0   = Sb + 1179648;         // 1,179,648
    float* wl   = H0 + 1179648;         // 512
    unsigned short* spT_b = (unsigned short*)(wl + 512);   // 1,179,648
    unsigned short* xs_b  = spT_b + 1179648;               // 2,359,296
    unsigned short* yb_b  = xs_b + 2359296;                // 2,359,296
    unsigned short* Wi_b  = yb_b + 2359296;                // 262,144
    unsigned short* Wx_b  = Wi_b + 262144;                 // 40,960
    unsigned short* Wo_b  = Wx_b + 40960;                  // 131,072

    // weight conversions (all scales at once)
    k_cvt<<<(262144 + 255) / 256, 256, 0, stream>>>(Wi, Wi_b, 262144);
    k_cvt<<<(40960 + 255) / 256, 256, 0, stream>>>(Wx, Wx_b, 40960);
    k_cvt<<<(131072 + 255) / 256, 256, 0, stream>>>(Wo, Wo_b, 131072);

    for (int i = 0; i < 4; ++i) {
        const float* wc_i   = wc   + (size_t)i * 256 * 4;
        const float* bc_i   = bcv  + (size_t)i * 256;
        const float* Wdt_i  = Wdt  + (size_t)i * 256 * 8;
        const float* bdt_i  = bdt  + (size_t)i * 256;
        const float* Alog_i = Alog + (size_t)i * 256 * 16;
        const float* D_i    = Dp   + (size_t)i * 256;
        const unsigned short* Wi_bi = Wi_b + (size_t)i * 512 * 128;
        const unsigned short* Wx_bi = Wx_b + (size_t)i * 40 * 256;
        const unsigned short* Wo_bi = Wo_b + (size_t)i * 128 * 256;

        k_prep<<<512, 256, 0, stream>>>(x, i ? out : nullptr, i, x_i, spT_b, wl);
        k_gemm_mfma<<<dim3(8, 72), 256, 0, stream>>>(spT_b, Wi_bi, xz, 9216, 512, 128);
        k_conv<<<9216, 256, 0, stream>>>(xz, wc_i, bc_i, xs_f, xs_b);
        k_gemm_mfma<<<dim3(1, 72), 256, 0, stream>>>(xs_b, Wx_bi, dbc, 9216, 40, 256);
        k_scan1<<<dim3(NC, BB), 256, 0, stream>>>(xs_f, dbc, Alog_i, Wdt_i, bdt_i, Pb, Sb);
        k_scan2<<<BB, 256, 0, stream>>>(Pb, Sb, H0);
        k_scan3<<<dim3(NC, BB), 256, 0, stream>>>(xs_f, dbc, Alog_i, Wdt_i, bdt_i, D_i, xz, H0, yb_b);
        k_gemm_mfma<<<dim3(2, 72), 256, 0, stream>>>(yb_b, Wo_bi, xm, 9216, 128, 256);
        k_gate<<<512, 256, 0, stream>>>(x_i, xm, wl, out, i);
    }
}